// Round 4
// baseline (227.090 us; speedup 1.0000x reference)
//
#include <hip/hip_runtime.h>
#include <hip/hip_bf16.h>
#include <math.h>

#define NTOT  8192
#define DIM   512
#define BATCH (NTOT/2)
#define TEMP_INV 5.0f   // 1/0.2
#define NBLK2 1056      // tiles (bi,bj): bj in [0,32), bi in [0, 2*bj+2)
#define GCH   16        // gram K-chunks (512 samples each)

typedef __attribute__((ext_vector_type(8))) short bf16x8;
typedef __attribute__((ext_vector_type(4))) float f32x4;

__device__ __forceinline__ float b2f(unsigned short u)
{
    unsigned int x = (unsigned int)u << 16;
    float f; __builtin_memcpy(&f, &x, 4); return f;
}

__device__ __forceinline__ unsigned int pack_bf16_2(float a, float b)
{
    __hip_bfloat16 ha = __float2bfloat16(a), hb = __float2bfloat16(b);
    unsigned short ua, ub;
    __builtin_memcpy(&ua, &ha, 2); __builtin_memcpy(&ub, &hb, 2);
    return (unsigned int)ua | ((unsigned int)ub << 16);
}

// ---------------- normalize: one wave per row ----------------
__global__ __launch_bounds__(256)
void normalize_k(const float* __restrict__ z, __hip_bfloat16* __restrict__ zn)
{
    const int lane = threadIdx.x & 63, wave = threadIdx.x >> 6;
    const int row  = blockIdx.x * 4 + wave;
    const float4* zr = (const float4*)(z + (size_t)row * DIM);
    const float4 a = zr[lane];
    const float4 b = zr[lane + 64];
    float ss = a.x*a.x + a.y*a.y + a.z*a.z + a.w*a.w
             + b.x*b.x + b.y*b.y + b.z*b.z + b.w*b.w;
    #pragma unroll
    for (int off = 1; off < 64; off <<= 1) ss += __shfl_xor(ss, off);
    const float inv = 1.0f / fmaxf(sqrtf(ss), 1e-12f);
    uint2* zo = (uint2*)(zn + (size_t)row * DIM);
    uint2 o0, o1;
    o0.x = pack_bf16_2(a.x * inv, a.y * inv);
    o0.y = pack_bf16_2(a.z * inv, a.w * inv);
    o1.x = pack_bf16_2(b.x * inv, b.y * inv);
    o1.y = pack_bf16_2(b.z * inv, b.w * inv);
    zo[lane]      = o0;
    zo[lane + 64] = o1;
}

// ---------------- transpose zn -> znT [512][8192], fused column sums S ----------------
__global__ __launch_bounds__(256)
void transpose_colsum_k(const __hip_bfloat16* __restrict__ zn,
                        __hip_bfloat16* __restrict__ znT,
                        float* __restrict__ S)
{
    __shared__ unsigned short T[64][72];
    __shared__ float Scol[64];
    const int tid = threadIdx.x;
    const int bs = blockIdx.x & 127;
    const int bd = blockIdx.x >> 7;
    const int s0 = bs * 64, d0 = bd * 64;
    if (tid < 64) Scol[tid] = 0.f;
    const int rr = tid >> 3;
    const int c8 = (tid & 7) * 8;
    float part[8];
    #pragma unroll
    for (int j = 0; j < 8; ++j) part[j] = 0.f;
    #pragma unroll
    for (int h = 0; h < 2; ++h) {
        const int row = rr + h * 32;
        const bf16x8 v = *(const bf16x8*)(zn + (size_t)(s0 + row) * DIM + d0 + c8);
        *(bf16x8*)&T[row][c8] = v;
        #pragma unroll
        for (int j = 0; j < 8; ++j) part[j] += b2f((unsigned short)v[j]);
    }
    __syncthreads();
    #pragma unroll
    for (int h = 0; h < 2; ++h) {
        const int d = rr + h * 32;
        bf16x8 ov;
        #pragma unroll
        for (int j = 0; j < 8; ++j) ov[j] = (short)T[c8 + j][d];
        *(bf16x8*)(znT + (size_t)(d0 + d) * NTOT + s0 + c8) = ov;
    }
    #pragma unroll
    for (int j = 0; j < 8; ++j) atomicAdd(&Scol[c8 + j], part[j]);
    __syncthreads();
    if (tid < 64) atomicAdd(&S[d0 + tid], Scol[tid]);
}

// ---------------- 128x128 MFMA K-loop (aux GEMMs): BK=32, NSTEP steps ----------------
__device__ __forceinline__ void issue4(const __hip_bfloat16* A, int sA,
                                       const __hip_bfloat16* B, int sB,
                                       int gk, unsigned short* Ad, unsigned short* Bd,
                                       int wave, int lane)
{
    const int f_l = lane & 15, q_l = lane >> 4;
    #pragma unroll
    for (int q = 0; q < 2; ++q) {
        const int s = wave * 2 + q;
        const __hip_bfloat16* ga = A + (size_t)(s * 16 + f_l) * sA + gk + q_l * 8;
        const __hip_bfloat16* gb = B + (size_t)(s * 16 + f_l) * sB + gk + q_l * 8;
        __builtin_amdgcn_global_load_lds(
            (const __attribute__((address_space(1))) unsigned int*)ga,
            (__attribute__((address_space(3))) unsigned int*)(Ad + s * 512 + lane * 8),
            16, 0, 0);
        __builtin_amdgcn_global_load_lds(
            (const __attribute__((address_space(1))) unsigned int*)gb,
            (__attribute__((address_space(3))) unsigned int*)(Bd + s * 512 + lane * 8),
            16, 0, 0);
    }
}

template<int NSTEP>
__device__ __forceinline__ void mm_kloop(const __hip_bfloat16* A, int sA,
                                         const __hip_bfloat16* B, int sB,
                                         unsigned short (*As)[4096],
                                         unsigned short (*Bs)[4096],
                                         f32x4 acc[4][4], int wave, int lane)
{
    const int wr = wave >> 1, wc = wave & 1;
    issue4(A, sA, B, sB, 0,  As[0], Bs[0], wave, lane);
    issue4(A, sA, B, sB, 32, As[1], Bs[1], wave, lane);
    #pragma unroll
    for (int ki = 0; ki < NSTEP; ++ki) {
        if (ki < NSTEP - 1) asm volatile("s_waitcnt vmcnt(4)\n\ts_barrier" ::: "memory");
        else                asm volatile("s_waitcnt vmcnt(0)\n\ts_barrier" ::: "memory");
        __builtin_amdgcn_sched_barrier(0);
        if (ki + 2 < NSTEP)
            issue4(A, sA, B, sB, (ki + 2) * 32, As[(ki + 2) % 3], Bs[(ki + 2) % 3], wave, lane);
        const unsigned short* Ap = As[ki % 3];
        const unsigned short* Bp = Bs[ki % 3];
        bf16x8 af[4], bfr[4];
        #pragma unroll
        for (int r = 0; r < 4; ++r)
            af[r] = *(const bf16x8*)(Ap + (wr * 4 + r) * 512 + lane * 8);
        #pragma unroll
        for (int c = 0; c < 4; ++c)
            bfr[c] = *(const bf16x8*)(Bp + (wc * 4 + c) * 512 + lane * 8);
        #pragma unroll
        for (int r = 0; r < 4; ++r)
            #pragma unroll
            for (int c = 0; c < 4; ++c)
                acc[r][c] = __builtin_amdgcn_mfma_f32_16x16x32_bf16(af[r], bfr[c], acc[r][c], 0, 0, 0);
    }
}

// ---------------- Gram: G = zn^T zn via znT, per-chunk partials ----------------
__global__ __launch_bounds__(256, 3)
void gram_k(const __hip_bfloat16* __restrict__ znT, float* __restrict__ Gpart)
{
    __shared__ unsigned short As[3][4096];
    __shared__ unsigned short Bs[3][4096];
    const int tid = threadIdx.x, wave = tid >> 6, lane = tid & 63;
    const int f_l = lane & 15, q_l = lane >> 4;
    const int t = blockIdx.x & 15, ch = blockIdx.x >> 4;
    const int di = (t >> 2) * 128, dj = (t & 3) * 128;
    const int wr = wave >> 1, wc = wave & 1;
    f32x4 acc[4][4];
    #pragma unroll
    for (int r = 0; r < 4; ++r)
        #pragma unroll
        for (int c = 0; c < 4; ++c) acc[r][c] = (f32x4){0.f, 0.f, 0.f, 0.f};
    mm_kloop<16>(znT + (size_t)di * NTOT + ch * 512, NTOT,
                 znT + (size_t)dj * NTOT + ch * 512, NTOT, As, Bs, acc, wave, lane);
    float* gp = Gpart + (size_t)ch * (512 * 512);
    #pragma unroll
    for (int r = 0; r < 4; ++r)
        #pragma unroll
        for (int c = 0; c < 4; ++c)
            #pragma unroll
            for (int u = 0; u < 4; ++u) {
                const int row = di + wr * 64 + r * 16 + q_l * 4 + u;
                const int col = dj + wc * 64 + c * 16 + f_l;
                gp[row * 512 + col] = acc[r][c][u];
            }
}

// ---------------- reduce GCH partials -> bf16 G ----------------
__global__ __launch_bounds__(256)
void gram_fin_k(const float* __restrict__ Gpart, __hip_bfloat16* __restrict__ G1)
{
    const int i = (blockIdx.x * 256 + threadIdx.x) * 4;
    float4 s = {0.f, 0.f, 0.f, 0.f};
    #pragma unroll
    for (int ch = 0; ch < GCH; ++ch) {
        const float4 v = *(const float4*)(Gpart + (size_t)ch * (512 * 512) + i);
        s.x += v.x; s.y += v.y; s.z += v.z; s.w += v.w;
    }
    uint2 o;
    o.x = pack_bf16_2(s.x, s.y);
    o.y = pack_bf16_2(s.z, s.w);
    *(uint2*)(G1 + i) = o;
}

// ---------------- rowsumsq_i = zn_i G zn_i^T via H = zn.G, split-K ----------------
__global__ __launch_bounds__(256, 3)
void rowstats_k(const __hip_bfloat16* __restrict__ zn,
                const __hip_bfloat16* __restrict__ G1,
                float* __restrict__ rowsumsq)
{
    __shared__ unsigned short As[3][4096];
    __shared__ unsigned short Bs[3][4096];
    const int tid = threadIdx.x, wave = tid >> 6, lane = tid & 63;
    const int f_l = lane & 15, q_l = lane >> 4;
    const int R0 = (blockIdx.x >> 3) * 128;
    const int C0 = ((blockIdx.x >> 1) & 3) * 128;
    const int kh = (blockIdx.x & 1) * 256;
    const int wr = wave >> 1, wc = wave & 1;
    f32x4 acc[4][4];
    #pragma unroll
    for (int r = 0; r < 4; ++r)
        #pragma unroll
        for (int c = 0; c < 4; ++c) acc[r][c] = (f32x4){0.f, 0.f, 0.f, 0.f};
    mm_kloop<8>(zn + (size_t)R0 * DIM + kh, DIM, G1 + (size_t)C0 * DIM + kh, DIM,
                As, Bs, acc, wave, lane);
    #pragma unroll
    for (int r = 0; r < 4; ++r) {
        #pragma unroll
        for (int u = 0; u < 4; ++u) {
            const int i = R0 + wr * 64 + r * 16 + q_l * 4 + u;
            float p = 0.f;
            #pragma unroll
            for (int c = 0; c < 4; ++c) {
                const int col = C0 + wc * 64 + c * 16 + f_l;
                unsigned short zb;
                __builtin_memcpy(&zb, zn + (size_t)i * DIM + col, 2);
                p += acc[r][c][u] * b2f(zb);
            }
            p += __shfl_xor(p, 1); p += __shfl_xor(p, 2);
            p += __shfl_xor(p, 4); p += __shfl_xor(p, 8);
            if (f_l == 0) atomicAdd(&rowsumsq[i], p);
        }
    }
}

// ---------------- stats finalize (rowsum = zn_i.S) + positive pairs fused ----------------
__global__ __launch_bounds__(256)
void finalize_pos_k(const __hip_bfloat16* __restrict__ zn,
                    const float* __restrict__ S,
                    const float* __restrict__ rowsumsq,
                    const int* __restrict__ labels,
                    float* __restrict__ mu_d,
                    float* __restrict__ inv2s2,
                    double* __restrict__ pos_acc)
{
    const int lane = threadIdx.x & 63, wave = threadIdx.x >> 6;
    const int row = blockIdx.x * 4 + wave;
    const bf16x8 v = *(const bf16x8*)(zn + (size_t)row * DIM + lane * 8);
    const float4 sa = *(const float4*)(S + lane * 8);
    const float4 sb = *(const float4*)(S + lane * 8 + 4);
    float acc = b2f((unsigned short)v[0]) * sa.x + b2f((unsigned short)v[1]) * sa.y
              + b2f((unsigned short)v[2]) * sa.z + b2f((unsigned short)v[3]) * sa.w
              + b2f((unsigned short)v[4]) * sb.x + b2f((unsigned short)v[5]) * sb.y
              + b2f((unsigned short)v[6]) * sb.z + b2f((unsigned short)v[7]) * sb.w;
    float vp = 0.f;
    if (row < BATCH) {
        const bf16x8 w = *(const bf16x8*)(zn + (size_t)(row + BATCH) * DIM + lane * 8);
        #pragma unroll
        for (int j = 0; j < 8; ++j)
            vp += b2f((unsigned short)v[j]) * b2f((unsigned short)w[j]);
    }
    #pragma unroll
    for (int off = 1; off < 64; off <<= 1) {
        acc += __shfl_xor(acc, off);
        vp  += __shfl_xor(vp, off);
    }
    if (lane == 0) {
        const float s  = acc;
        const float sq = rowsumsq[row];
        const float mean_sim = s * (1.0f / NTOT);
        const float var = (sq - s * mean_sim) * (1.0f / (NTOT - 1));
        mu_d[row]   = 1.0f - mean_sim;
        inv2s2[row] = 1.0f / (2.0f * var);
        if (row < BATCH && labels[row] == labels[row + BATCH])
            atomicAdd(pos_acc, (double)__expf(vp * TEMP_INV));
    }
}

// ---------------- fused triangle GEMM + exp epilogue: 128x256 tiles, 64x128 wave tiles ----------------
__global__ __launch_bounds__(256, 2)
void sim_neg_k(const __hip_bfloat16* __restrict__ zn,
               const int*   __restrict__ labels,
               const float* __restrict__ mu_d,
               const float* __restrict__ inv2s2,
               double* __restrict__ neg_acc)
{
    __shared__ unsigned short As[3][4096];   // 8 KB per stage: 128 rows x 32 k
    __shared__ unsigned short Bs[3][8192];   // 16 KB per stage: 256 rows x 32 k
    __shared__ float redbuf[4];
    const int tid = threadIdx.x, wave = tid >> 6, lane = tid & 63;
    const int f_l = lane & 15, q_l = lane >> 4;

    // decode t = bj*(bj+1) + bi, 0 <= bi <= 2*bj+1
    const int t = blockIdx.x;
    int b = (int)((sqrtf(4.0f * (float)t + 1.0f) - 1.0f) * 0.5f);
    while ((b + 1) * (b + 2) <= t) ++b;
    while (b * (b + 1) > t)       --b;
    const int bj = b, bi = t - b * (b + 1);
    const int R0 = bi * 128, C0 = bj * 256;
    const int wr = wave >> 1, wc = wave & 1;

    const __hip_bfloat16* A = zn + (size_t)R0 * DIM;
    const __hip_bfloat16* B = zn + (size_t)C0 * DIM;

    auto issue = [&](int gk, int buf) {
        #pragma unroll
        for (int q = 0; q < 2; ++q) {
            const int s = wave * 2 + q;                    // A segs 0..7
            const __hip_bfloat16* ga = A + (size_t)(s * 16 + f_l) * DIM + gk + q_l * 8;
            __builtin_amdgcn_global_load_lds(
                (const __attribute__((address_space(1))) unsigned int*)ga,
                (__attribute__((address_space(3))) unsigned int*)(As[buf] + s * 512 + lane * 8),
                16, 0, 0);
        }
        #pragma unroll
        for (int q = 0; q < 4; ++q) {
            const int s = wave * 4 + q;                    // B segs 0..15
            const __hip_bfloat16* gb = B + (size_t)(s * 16 + f_l) * DIM + gk + q_l * 8;
            __builtin_amdgcn_global_load_lds(
                (const __attribute__((address_space(1))) unsigned int*)gb,
                (__attribute__((address_space(3))) unsigned int*)(Bs[buf] + s * 512 + lane * 8),
                16, 0, 0);
        }
    };

    f32x4 acc[4][8];
    #pragma unroll
    for (int r = 0; r < 4; ++r)
        #pragma unroll
        for (int c = 0; c < 8; ++c) acc[r][c] = (f32x4){0.f, 0.f, 0.f, 0.f};

    issue(0, 0);
    issue(32, 1);
    #pragma unroll
    for (int ki = 0; ki < 16; ++ki) {
        // 6 loads/wave/step: wait for buf[ki]'s 6 (oldest); buf[ki+1]'s 6 stay in flight.
        if (ki < 15) asm volatile("s_waitcnt vmcnt(6)\n\ts_barrier" ::: "memory");
        else         asm volatile("s_waitcnt vmcnt(0)\n\ts_barrier" ::: "memory");
        __builtin_amdgcn_sched_barrier(0);
        if (ki + 2 < 16) issue((ki + 2) * 32, (ki + 2) % 3);
        const unsigned short* Ap = As[ki % 3];
        const unsigned short* Bp = Bs[ki % 3];
        bf16x8 af[4], bfr[8];
        #pragma unroll
        for (int r = 0; r < 4; ++r)
            af[r] = *(const bf16x8*)(Ap + (wr * 4 + r) * 512 + lane * 8);
        #pragma unroll
        for (int c = 0; c < 8; ++c)
            bfr[c] = *(const bf16x8*)(Bp + (wc * 8 + c) * 512 + lane * 8);
        #pragma unroll
        for (int r = 0; r < 4; ++r)
            #pragma unroll
            for (int c = 0; c < 8; ++c)
                acc[r][c] = __builtin_amdgcn_mfma_f32_16x16x32_bf16(af[r], bfr[c], acc[r][c], 0, 0, 0);
    }

    // epilogue: element (i,j) processed iff j > i; always add BOTH stat-sides.
    int labj[8]; float muj[8], isj[8];
    #pragma unroll
    for (int c = 0; c < 8; ++c) {
        const int j = C0 + wc * 128 + c * 16 + f_l;
        labj[c] = labels[j]; muj[c] = mu_d[j]; isj[c] = inv2s2[j];
    }
    float local = 0.f;
    #pragma unroll
    for (int r = 0; r < 4; ++r) {
        const int ib = R0 + wr * 64 + r * 16 + q_l * 4;
        #pragma unroll
        for (int u = 0; u < 4; ++u) {
            const int   i  = ib + u;
            const int   li = labels[i];
            const float mi = mu_d[i];
            const float vi = inv2s2[i];
            #pragma unroll
            for (int c = 0; c < 8; ++c) {
                const int j = C0 + wc * 128 + c * 16 + f_l;
                const float s  = acc[r][c][u];
                const float d  = 1.0f - s;
                const float dj = d - muj[c];
                const float di = d - mi;
                const float e = __expf(s * TEMP_INV + dj * dj * isj[c])
                              + __expf(s * TEMP_INV + di * di * vi);
                local += (j > i && li != labj[c]) ? e : 0.f;
            }
        }
    }
    #pragma unroll
    for (int off = 1; off < 64; off <<= 1) local += __shfl_xor(local, off);
    if (lane == 0) redbuf[wave] = local;
    __syncthreads();
    if (tid == 0)
        atomicAdd(neg_acc, (double)(redbuf[0] + redbuf[1] + redbuf[2] + redbuf[3]));
}

// ---------------- final loss ----------------
__global__ void loss_k(const double* __restrict__ accs, float* __restrict__ out)
{
    const double neg = accs[0], pos = accs[1];
    out[0] = (float)(-log(pos / (pos + neg)));
}

extern "C" void kernel_launch(void* const* d_in, const int* in_sizes, int n_in,
                              void* d_out, int out_size, void* d_ws, size_t ws_size,
                              hipStream_t stream)
{
    const float* z      = (const float*)d_in[0];
    const int*   labels = (const int*)d_in[1];
    float* out = (float*)d_out;

    char* ws = (char*)d_ws;
    __hip_bfloat16* zn  = (__hip_bfloat16*)ws;                                // 8 MiB
    __hip_bfloat16* znT = (__hip_bfloat16*)(ws + ((size_t)8 << 20));          // 8 MiB
    float*  Gpart    = (float*)(ws + ((size_t)16 << 20));                     // GCH MiB
    float*  S        = (float*)(ws + ((size_t)(16 + GCH) << 20));             // 2 KiB
    float*  rowsumsq = S + 512;                                               // 32 KiB
    double* accs     = (double*)(rowsumsq + NTOT);                            // [0]=neg [1]=pos
    float*  mu_d     = (float*)(accs + 2);                                    // 32 KiB
    float*  inv2s2   = mu_d + NTOT;                                           // 32 KiB
    __hip_bfloat16* G1 = (__hip_bfloat16*)(inv2s2 + NTOT);                    // 512 KiB

    hipMemsetAsync(S, 0, (size_t)(512 + NTOT) * sizeof(float) + 2 * sizeof(double), stream);

    normalize_k<<<NTOT / 4, 256, 0, stream>>>(z, zn);
    transpose_colsum_k<<<1024, 256, 0, stream>>>(zn, znT, S);
    gram_k<<<16 * GCH, 256, 0, stream>>>(znT, Gpart);
    gram_fin_k<<<256, 256, 0, stream>>>(Gpart, G1);
    rowstats_k<<<512, 256, 0, stream>>>(zn, G1, rowsumsq);
    finalize_pos_k<<<NTOT / 4, 256, 0, stream>>>(zn, S, rowsumsq, labels, mu_d, inv2s2, accs + 1);
    sim_neg_k<<<NBLK2, 256, 0, stream>>>(zn, labels, mu_d, inv2s2, accs);
    loss_k<<<1, 1, 0, stream>>>(accs, out);
}